// Round 7
// baseline (981.532 us; speedup 1.0000x reference)
//
#include <hip/hip_runtime.h>
#include <math.h>

#define NB    2048
#define NSEG  20
#define MAXIT 48

typedef short bf8_t __attribute__((ext_vector_type(8)));
typedef float f32x4 __attribute__((ext_vector_type(4)));

#define cA21 ((float)0.161)
#define cA31 ((float)-0.008480655492356989)
#define cA32 ((float)0.335480655492357)
#define cA41 ((float)2.8971530571054935)
#define cA42 ((float)-6.359448489975075)
#define cA43 ((float)4.3622954328695815)
#define cA51 ((float)5.325864828439257)
#define cA52 ((float)-11.748883564062828)
#define cA53 ((float)7.4955393428898365)
#define cA54 ((float)-0.09249506636175525)
#define cA61 ((float)5.86145544294642)
#define cA62 ((float)-12.92096931784711)
#define cA63 ((float)8.159367898576159)
#define cA64 ((float)-0.071584973281401)
#define cA65 ((float)-0.028269050394068383)
#define cB1  ((float)0.09646076681806523)
#define cB2  ((float)0.01)
#define cB3  ((float)0.4798896504144996)
#define cB4  ((float)1.379008574103742)
#define cB5  ((float)-3.290069515436081)
#define cB6  ((float)2.324710524099774)
#define cE1  ((float)-0.001780011052225777)
#define cE2  ((float)-0.0008164344596567469)
#define cE3  ((float)0.007880878010261995)
#define cE4  ((float)-0.1447110071732629)
#define cE5  ((float)0.5823571654525552)
#define cE6  ((float)-0.45808210592918697)
#define cE7  ((float)0.015151515151515152)

__device__ __forceinline__ void split2(float x, short &hi, short &lo) {
    unsigned u = __float_as_uint(x);
    hi = (short)(u >> 16);
    float r = x - __uint_as_float(u & 0xFFFF0000u);
    lo = (short)(__float_as_uint(r) >> 16);
}

__device__ __forceinline__ short bf16rne(float x) {
    unsigned u = __float_as_uint(x);
    return (short)((u + 0x7FFFu + ((u >> 16) & 1u)) >> 16);
}

__device__ __forceinline__ float softplus_f(float x) {
    float t = exp2f(-fabsf(x) * 1.442695040888963f);
    return fmaxf(x, 0.0f) + log2f(1.0f + t) * 0.6931471805599453f;
}

__device__ __forceinline__ unsigned pk(short a, short b) {
    return ((unsigned)(unsigned short)a) | (((unsigned)(unsigned short)b) << 16);
}

// 512 threads = 8 waves; 8 elements per block in lockstep (r3 structure).
// Stage args: hi+lo split-bf16 (3-product GEMM). Hidden acts h1/h2: bf16-RNE
// hi-only (2-product GEMM: Al*Bh + Ah*Bh) -> halves LDS traffic, shorter epi.
// ODE state in E-layout: wave = element, lane = dim. kcur LDS roundtrip.
__global__ __launch_bounds__(512)
void ode_kernel(const float* __restrict__ history,
                const float* __restrict__ W1, const float* __restrict__ b1,
                const float* __restrict__ W2, const float* __restrict__ b2,
                const float* __restrict__ W3, const float* __restrict__ b3,
                float* __restrict__ out)
{
    // chunk = 4 quads * (16 cols * 8 + 8 pad) = 544 shorts
    __shared__ alignas(16) short argH[2 * 544], argL[2 * 544];
    __shared__ alignas(16) short h1H[4 * 544];
    __shared__ alignas(16) short h2H[4 * 544];
    __shared__ alignas(16) float kcur[8 * 68];   // [e][d], row-padded

    const int tid  = threadIdx.x;
    const int wave = tid >> 6, lane = tid & 63;
    const int quad = lane >> 4, col = lane & 15;
    const int jb   = 16 * wave + 4 * quad;        // this lane's D-row base
    const bool w03 = (wave < 4);

    // ---- weight A-fragments (bf16 hi/lo), layout verified rounds 3-6 ----
    bf8_t A1h[2], A1l[2], A2h[4], A2l[4], A3h[4], A3l[4];
#pragma unroll
    for (int c = 0; c < 2; ++c) {
        const float* p = W1 + (size_t)(16 * wave + col) * 64 + 32 * c + 8 * quad;
        bf8_t h, l;
#pragma unroll
        for (int j = 0; j < 8; ++j) { short hs, ls; split2(p[j], hs, ls); h[j] = hs; l[j] = ls; }
        A1h[c] = h; A1l[c] = l;
    }
#pragma unroll
    for (int c = 0; c < 4; ++c) {
        const float* p = W2 + (size_t)(16 * wave + col) * 128 + 32 * c + 8 * quad;
        bf8_t h, l;
#pragma unroll
        for (int j = 0; j < 8; ++j) { short hs, ls; split2(p[j], hs, ls); h[j] = hs; l[j] = ls; }
        A2h[c] = h; A2l[c] = l;
    }
    f32x4 b3f = {0.f, 0.f, 0.f, 0.f};
    if (w03) {
#pragma unroll
        for (int c = 0; c < 4; ++c) {
            const float* p = W3 + (size_t)(16 * wave + col) * 128 + 32 * c + 8 * quad;
            bf8_t h, l;
#pragma unroll
            for (int j = 0; j < 8; ++j) { short hs, ls; split2(p[j], hs, ls); h[j] = hs; l[j] = ls; }
            A3h[c] = h; A3l[c] = l;
        }
        b3f = *(const f32x4*)(b3 + jb);
    }
    const f32x4 b1f = *(const f32x4*)(b1 + jb);
    const f32x4 b2f = *(const f32x4*)(b2 + jb);

    // row-base LDS index for C-layout-derived writes
    const int wIdx = (jb >> 5) * 544 + ((jb >> 3) & 3) * 136 + (jb & 7);

    // 3-product (hi+lo B) for the stage-arg GEMM
    auto gemm3 = [&](const bf8_t* Ah, const bf8_t* Al,
                     const short* BH, const short* BL, int nch) -> f32x4 {
        bf8_t bh[4], bl[4];
#pragma unroll 4
        for (int c = 0; c < nch; ++c) {
            const int off = c * 544 + quad * 136 + col * 8;
            bh[c] = *(const bf8_t*)(BH + off);
            bl[c] = *(const bf8_t*)(BL + off);
        }
        f32x4 p1 = {0.f, 0.f, 0.f, 0.f}, p2 = {0.f, 0.f, 0.f, 0.f}, p3 = {0.f, 0.f, 0.f, 0.f};
#pragma unroll 4
        for (int c = 0; c < nch; ++c) {
            p1 = __builtin_amdgcn_mfma_f32_16x16x32_bf16(Al[c], bh[c], p1, 0, 0, 0);
            p2 = __builtin_amdgcn_mfma_f32_16x16x32_bf16(Ah[c], bl[c], p2, 0, 0, 0);
            p3 = __builtin_amdgcn_mfma_f32_16x16x32_bf16(Ah[c], bh[c], p3, 0, 0, 0);
        }
        f32x4 o;
#pragma unroll
        for (int r = 0; r < 4; ++r) o[r] = (p1[r] + p2[r]) + p3[r];
        return o;
    };

    // 2-product (hi-only B) for hidden-layer GEMMs
    auto gemm2 = [&](const bf8_t* Ah, const bf8_t* Al, const short* BH, int nch) -> f32x4 {
        bf8_t bh[4];
#pragma unroll 4
        for (int c = 0; c < nch; ++c)
            bh[c] = *(const bf8_t*)(BH + c * 544 + quad * 136 + col * 8);
        f32x4 p1 = {0.f, 0.f, 0.f, 0.f}, p3 = {0.f, 0.f, 0.f, 0.f};
#pragma unroll 4
        for (int c = 0; c < nch; ++c) {
            p1 = __builtin_amdgcn_mfma_f32_16x16x32_bf16(Al[c], bh[c], p1, 0, 0, 0);
            p3 = __builtin_amdgcn_mfma_f32_16x16x32_bf16(Ah[c], bh[c], p3, 0, 0, 0);
        }
        f32x4 o;
#pragma unroll
        for (int r = 0; r < 4; ++r) o[r] = p1[r] + p3[r];
        return o;
    };

    // softplus + bf16-RNE, single-buffer write (cols<8 lanes)
    auto epiH = [&](f32x4 pre, f32x4 bias, short* H) {
        if (col < 8) {
            short hh[4];
#pragma unroll
            for (int r = 0; r < 4; ++r)
                hh[r] = bf16rne(softplus_f(pre[r] + bias[r]));
            *(uint2*)(H + wIdx + col * 8) = make_uint2(pk(hh[0], hh[1]), pk(hh[2], hh[3]));
        }
    };

    // full MLP eval; argH/argL must be written. k lands in kcur.
    auto eval = [&]() {
        __syncthreads();
        f32x4 q1 = gemm3(A1h, A1l, argH, argL, 2);
        epiH(q1, b1f, h1H);
        __syncthreads();
        f32x4 q2 = gemm2(A2h, A2l, h1H, 4);
        epiH(q2, b2f, h2H);
        __syncthreads();
        if (w03) {
            f32x4 q3 = gemm2(A3h, A3l, h2H, 4);
            if (col < 8) {
                f32x4 kv;
#pragma unroll
                for (int r = 0; r < 4; ++r) kv[r] = q3[r] + b3f[r];
                *(f32x4*)(kcur + col * 68 + jb) = kv;
            }
        }
        __syncthreads();
    };

    // ---- state (E-layout: wave = element, lane = dim) ----
    const int elem = blockIdx.x * 8 + wave;
    const int aidx = (lane >> 5) * 544 + ((lane >> 3) & 3) * 136 + wave * 8 + (lane & 7);

    float y  = history[((size_t)elem * 15 + 14) * 64 + lane];
    float dt = 0.1f;
    float k1, k2, k3, k4, k5, k6;

    // initial k1 = f(y)  (FSAL thereafter)
    {
        short hi, lo; split2(y, hi, lo);
        argH[aidx] = hi; argL[aidx] = lo;
        eval();
        k1 = kcur[wave * 68 + lane];
    }

#pragma unroll 1
    for (int seg = 1; seg <= NSEG; ++seg) {
        const float t1 = (float)seg;
        float t = t1 - 1.0f;
        bool done = false;

#pragma unroll 1
        for (int it = 0; it < MAXIT; ++it) {
            const float dt_c = fminf(dt, t1 - t);
            const float h = dt_c;
            float y5v = 0.f, k7v = 0.f;

#pragma unroll 1
            for (int st = 2; st <= 7; ++st) {
                float sum;
                switch (st) {
                    case 2: sum = cA21 * k1; break;
                    case 3: sum = fmaf(cA31, k1, cA32 * k2); break;
                    case 4: sum = fmaf(cA41, k1, fmaf(cA42, k2, cA43 * k3)); break;
                    case 5: sum = fmaf(cA51, k1, fmaf(cA52, k2, fmaf(cA53, k3, cA54 * k4))); break;
                    case 6: sum = fmaf(cA61, k1, fmaf(cA62, k2, fmaf(cA63, k3, fmaf(cA64, k4, cA65 * k5)))); break;
                    default: sum = fmaf(cB1, k1, fmaf(cB2, k2, fmaf(cB3, k3, fmaf(cB4, k4, fmaf(cB5, k5, cB6 * k6))))); break;
                }
                float arg = fmaf(h, sum, y);
                if (st == 7) y5v = arg;
                short hi, lo; split2(arg, hi, lo);
                argH[aidx] = hi; argL[aidx] = lo;
                eval();
                float kv = kcur[wave * 68 + lane];
                switch (st) {
                    case 2: k2 = kv; break;
                    case 3: k3 = kv; break;
                    case 4: k4 = kv; break;
                    case 5: k5 = kv; break;
                    case 6: k6 = kv; break;
                    default: k7v = kv; break;
                }
            }

            // error norm: within-wave shuffle reduce (E-layout)
            float esum = fmaf(cE1, k1, fmaf(cE2, k2, fmaf(cE3, k3,
                         fmaf(cE4, k4, fmaf(cE5, k5, fmaf(cE6, k6, cE7 * k7v))))));
            float err = h * esum;
            float sc = fmaf(1e-3f, fmaxf(fabsf(y), fabsf(y5v)), 1e-6f);
            float r = err / sc;
            float rr = r * r;
#pragma unroll
            for (int off = 32; off > 0; off >>= 1) rr += __shfl_xor(rr, off, 64);
            float en = sqrtf(rr * (1.0f / 64.0f));

            bool accept = (en <= 1.0f) && !done;
            float fac = 0.9f * exp2f(-0.2f * log2f(fmaxf(en, 1e-10f)));
            fac = fminf(fmaxf(fac, 0.2f), 10.0f);

            if (accept) { t += dt_c; y = y5v; k1 = k7v; }   // FSAL
            if (!done) dt = dt_c * fac;
            done = done || (t >= t1 - 1e-8f);

            if (__syncthreads_and(done ? 1 : 0)) break;
        }

        out[((size_t)elem * NSEG + (seg - 1)) * 64 + lane] = y;
    }
}

extern "C" void kernel_launch(void* const* d_in, const int* in_sizes, int n_in,
                              void* d_out, int out_size, void* d_ws, size_t ws_size,
                              hipStream_t stream) {
    const float* history = (const float*)d_in[0];
    const float* W1 = (const float*)d_in[1];
    const float* b1 = (const float*)d_in[2];
    const float* W2 = (const float*)d_in[3];
    const float* b2 = (const float*)d_in[4];
    const float* W3 = (const float*)d_in[5];
    const float* b3 = (const float*)d_in[6];
    float* out = (float*)d_out;

    ode_kernel<<<dim3(NB / 8), dim3(512), 0, stream>>>(history, W1, b1, W2, b2, W3, b3, out);
}